// Round 8
// baseline (396.923 us; speedup 1.0000x reference)
//
#include <hip/hip_runtime.h>
#include <cstdint>
#include <cstring>

// ============================================================================
// NUTS on diagonal Gaussian, exact JAX-semantics replication.
//
// R7 -> R8 (theory: k_gather's ~780 inst of redundant per-block reduce+SM is
// the biggest remaining controllable cost; fold it into a tail block of
// k_traj0 via the R5 handshake — R5's handshake was correct, its failure was
// the serial 16x gather which stays parallel here):
//  * k_traj0: after partials, device-scope fetch_add(done[chain]); winner
//    (old==0xAAAAAAB9 poison-start || old==15 zero-start) reduces the chain's
//    partials + runs the SM + writes sel[chain] + flag[chain]=MAGIC.
//  * k_gather: if flag==MAGIC use sel (slim: load th0/prec/r0save, resim,
//    write); else fall back to local reduce+SM (correctness never depends on
//    the handshake).
//  * Merge/level dots share the (th_far-th_near) diff (-~150 inst).
// ============================================================================

#define PARTITIONABLE 1

constexpr int NCHAIN = 128;
constexpr int NDIM   = 16384;
constexpr int TPB    = 256;
constexpr int WGPC   = NDIM / (TPB * 4);     // 16 blocks per chain
constexpr int NP     = 256;                  // partial slots per chain-slot
constexpr int NSLOT  = 62;                   // 2*(26 nodes) + 2*(5 doublings)
constexpr int NNODE  = 26;
constexpr float EPS  = 0.05f;
constexpr uint32_t MAGIC = 0x5EC0DE5Au;

// ---------------------------------------------------------------- threefry --
__host__ __device__ static inline void tf2(uint32_t k0, uint32_t k1,
                                           uint32_t x0, uint32_t x1,
                                           uint32_t& o0, uint32_t& o1) {
  const uint32_t ks2 = k0 ^ k1 ^ 0x1BD11BDAu;
  x0 += k0; x1 += k1;
#define TF_R(r) { x0 += x1; x1 = (x1 << (r)) | (x1 >> (32 - (r))); x1 ^= x0; }
  TF_R(13) TF_R(15) TF_R(26) TF_R(6)
  x0 += k1;  x1 += ks2 + 1u;
  TF_R(17) TF_R(29) TF_R(16) TF_R(24)
  x0 += ks2; x1 += k0 + 2u;
  TF_R(13) TF_R(15) TF_R(26) TF_R(6)
  x0 += k0;  x1 += k1 + 3u;
  TF_R(17) TF_R(29) TF_R(16) TF_R(24)
  x0 += k1;  x1 += ks2 + 4u;
  TF_R(13) TF_R(15) TF_R(26) TF_R(6)
  x0 += ks2; x1 += k0 + 5u;
#undef TF_R
  o0 = x0; o1 = x1;
}

__device__ static inline float u01(uint32_t bits) {
  return __uint_as_float((bits >> 9) | 0x3f800000u) - 1.0f;
}

// XLA ErfInv32 (Giles), fma-exact
__device__ static inline float erfinv32(float x) {
  float w = -log1pf(-x * x);
  float p;
  if (w < 5.0f) {
    w -= 2.5f;
    p = 2.81022636e-08f;
    p = fmaf(p, w, 3.43273939e-07f);
    p = fmaf(p, w, -3.5233877e-06f);
    p = fmaf(p, w, -4.39150654e-06f);
    p = fmaf(p, w, 0.00021858087f);
    p = fmaf(p, w, -0.00125372503f);
    p = fmaf(p, w, -0.00417768164f);
    p = fmaf(p, w, 0.246640727f);
    p = fmaf(p, w, 1.50140941f);
  } else {
    w = sqrtf(w) - 3.0f;
    p = -0.000200214257f;
    p = fmaf(p, w, 0.000100950558f);
    p = fmaf(p, w, 0.00134934322f);
    p = fmaf(p, w, -0.00367342844f);
    p = fmaf(p, w, 0.00573950773f);
    p = fmaf(p, w, -0.0076224613f);
    p = fmaf(p, w, 0.00943887047f);
    p = fmaf(p, w, 1.00167406f);
    p = fmaf(p, w, 2.83297682f);
  }
  return p * x;
}

__device__ static inline float norm_from_bits(uint32_t bits) {
  const float lo = __uint_as_float(0xBF7FFFFFu);       // -(1 - 2^-24)
  float u = fmaxf(lo, fmaf(u01(bits), 2.0f, lo));
  return __uint_as_float(0x3FB504F3u) * erfinv32(u);   // sqrt(2) in f32
}

__device__ static inline float r0_elem(uint32_t k0, uint32_t k1, uint32_t i) {
#if PARTITIONABLE
  uint32_t a, c; tf2(k0, k1, 0u, i, a, c);
  return norm_from_bits(a ^ c);
#else
  const uint32_t H = (uint32_t)(NCHAIN * NDIM / 2);
  uint32_t a, c;
  if (i < H) { tf2(k0, k1, i, i + H, a, c); return norm_from_bits(a); }
  else       { tf2(k0, k1, i - H, i, a, c); return norm_from_bits(c); }
#endif
}

__device__ static inline float unif_chain(uint32_t k0, uint32_t k1, int b) {
#if PARTITIONABLE
  uint32_t a, c; tf2(k0, k1, 0u, (uint32_t)b, a, c);
  return u01(a ^ c);
#else
  uint32_t a, c;
  if (b < 64) { tf2(k0, k1, (uint32_t)b, (uint32_t)(b + 64), a, c); return u01(a); }
  else        { tf2(k0, k1, (uint32_t)(b - 64), (uint32_t)b, a, c); return u01(c); }
#endif
}

// ------------------------------------------------------------- DPP sums -----
#define DPP_ADD(x, ctrl, rm)                                                   \
  (x) += __int_as_float(__builtin_amdgcn_update_dpp(                           \
      0, __float_as_int(x), (ctrl), (rm), 0xf, true));

__device__ static inline float wave_sum63(float x) {   // full 64-lane, lane 63
  DPP_ADD(x, 0x111, 0xf)
  DPP_ADD(x, 0x112, 0xf)
  DPP_ADD(x, 0x114, 0xf)
  DPP_ADD(x, 0x118, 0xf)
  DPP_ADD(x, 0x142, 0xa)   // row_bcast:15 -> rows 1,3
  DPP_ADD(x, 0x143, 0xc)   // row_bcast:31 -> rows 2,3
  return x;
}
__device__ static inline float wave_sum15(float x) {   // row-of-16 sums, lane 15
  DPP_ADD(x, 0x111, 0xf)
  DPP_ADD(x, 0x112, 0xf)
  DPP_ADD(x, 0x114, 0xf)
  DPP_ADD(x, 0x118, 0xf)
  return x;
}

// ------------------------------------------------------- float4 arithmetic --
__device__ __forceinline__ float4 f4_pcfma(float he, const float4& pc,
                                           const float4& th, const float4& r) {
  return make_float4(fmaf(he, pc.x * th.x, r.x), fmaf(he, pc.y * th.y, r.y),
                     fmaf(he, pc.z * th.z, r.z), fmaf(he, pc.w * th.w, r.w));
}
__device__ __forceinline__ float4 f4_fma(float e, const float4& a, const float4& b) {
  return make_float4(fmaf(e, a.x, b.x), fmaf(e, a.y, b.y),
                     fmaf(e, a.z, b.z), fmaf(e, a.w, b.w));
}
__device__ __forceinline__ float4 f4_sub(const float4& a, const float4& b) {
  return make_float4(a.x - b.x, a.y - b.y, a.z - b.z, a.w - b.w);
}
__device__ __forceinline__ float f4_dot(const float4& a, const float4& b) {
  float d = a.x * b.x;
  d = fmaf(a.y, b.y, d);
  d = fmaf(a.z, b.z, d);
  d = fmaf(a.w, b.w, d);
  return d;
}

// ------------------------------------------------------------------ params --
struct Params {
  uint32_t nk0[NNODE], nk1[NNODE];  // buildtree k3 keys, post-order across j
  uint32_t ak0[5], ak1[5];          // main-loop ka keys
  int v[5];
};

// ------------------------------- trajectory state: NAMED float4 vars only ---
struct Traj {
  float4 th, r, tho, ro, pc;
  float4 nt0, nt1, nt2, nt3, nt4;
  float4 nr0, nr1, nr2, nr3, nr4;
};
template <int L> __device__ __forceinline__ float4& NT(Traj& t) {
  if constexpr (L == 0) return t.nt0; else if constexpr (L == 1) return t.nt1;
  else if constexpr (L == 2) return t.nt2; else if constexpr (L == 3) return t.nt3;
  else return t.nt4;
}
template <int L> __device__ __forceinline__ float4& NR(Traj& t) {
  if constexpr (L == 0) return t.nr0; else if constexpr (L == 1) return t.nr1;
  else if constexpr (L == 2) return t.nr2; else if constexpr (L == 3) return t.nr3;
  else return t.nr4;
}

// store one slot's row partials (4 per wave): pos = wv4 + row
__device__ __forceinline__ void store_partial(float* __restrict__ partials,
                                              int slot, int chain, int wv4,
                                              int lane, float v) {
  if ((lane & 15) == 15)
    partials[((size_t)slot * NCHAIN + chain) * NP + wv4 + (lane >> 4)] = v;
}

// merges after a leaf: K = 0..M-1, all indices constexpr
template <int P, int K, int M>
struct Merge {
  static __device__ __forceinline__ void run(Traj& t, float* __restrict__ partials,
                                             int chain, int wv4, int lane, int& slot) {
    if constexpr (K < M) {
      const float4 df = f4_sub(t.th, NT<P - 1 - K>(t));
      float d1 = f4_dot(df, NR<P - 1 - K>(t));   // (th_far-th_near)·r_near
      float d2 = f4_dot(df, t.r);                // (th_far-th_near)·r_far
      d1 = wave_sum15(d1);
      d2 = wave_sum15(d2);
      store_partial(partials, slot,     chain, wv4, lane, d1);
      store_partial(partials, slot + 1, chain, wv4, lane, d2);
      slot += 2;
      Merge<P, K + 1, M>::run(t, partials, chain, wv4, lane, slot);
    }
  }
};

template <int J, int I>
struct Leaf {
  static __device__ __forceinline__ void run(Traj& t, float e, float he,
                                             float* __restrict__ partials,
                                             int chain, int wv4, int lane, int& slot) {
    t.r  = f4_pcfma(-he, t.pc, t.th, t.r);
    t.th = f4_fma(e, t.r, t.th);
    t.r  = f4_pcfma(-he, t.pc, t.th, t.r);
    constexpr int P = __builtin_popcount((unsigned)I);
    NT<P>(t) = t.th; NR<P>(t) = t.r;
    constexpr int M = __builtin_ctz(~(unsigned)I);
    Merge<P, 0, M>::run(t, partials, chain, wv4, lane, slot);
    if constexpr (I + 1 < (1 << J))
      Leaf<J, I + 1>::run(t, e, he, partials, chain, wv4, lane, slot);
  }
};

// ------------------------- state machine: NAMED scalar slots + templates ----
struct SMs {
  int n0, s0, p0, n1, s1, p1, n2, s2, p2, n3, s3, p3, n4, s4, p4;
  int n, s, sel, slot, nodeidx, g;
};
template <int L> __device__ __forceinline__ int& SN(SMs& m) {
  if constexpr (L == 0) return m.n0; else if constexpr (L == 1) return m.n1;
  else if constexpr (L == 2) return m.n2; else if constexpr (L == 3) return m.n3;
  else return m.n4;
}
template <int L> __device__ __forceinline__ int& SS(SMs& m) {
  if constexpr (L == 0) return m.s0; else if constexpr (L == 1) return m.s1;
  else if constexpr (L == 2) return m.s2; else if constexpr (L == 3) return m.s3;
  else return m.s4;
}
template <int L> __device__ __forceinline__ int& SP(SMs& m) {
  if constexpr (L == 0) return m.p0; else if constexpr (L == 1) return m.p1;
  else if constexpr (L == 2) return m.p2; else if constexpr (L == 3) return m.p3;
  else return m.p4;
}

template <int P, int K, int M>
struct SMerge {
  static __device__ __forceinline__ void run(SMs& m, const float* dots_s,
                                             const float* unifs_s, float vj) {
    if constexpr (K < M) {
      constexpr int T = P - K;                       // second subtree slot
      int n1 = SN<T-1>(m), s1 = SS<T-1>(m), p1 = SP<T-1>(m);
      int n2 = SN<T>(m),   s2 = SS<T>(m),   p2 = SP<T>(m);
      float d1 = dots_s[m.slot], d2 = dots_s[m.slot + 1];
      m.slot += 2;
      float uu = unifs_s[m.nodeidx]; m.nodeidx++;
      int dn = n1 + n2; if (dn < 1) dn = 1;
      bool fl = (uu < (float)n2 / (float)dn) && (s1 >= 1);
      SP<T-1>(m) = fl ? p2 : p1;
      SS<T-1>(m) = (s1 != 0 && s2 != 0 &&
                    (vj * d1 >= 0.0f) && (vj * d2 >= 0.0f)) ? 1 : 0;
      SN<T-1>(m) = n1 + ((s1 >= 1) ? n2 : 0);
      SMerge<P, K + 1, M>::run(m, dots_s, unifs_s, vj);
    }
  }
};

template <int J, int I>
struct SLeaf {
  static __device__ __forceinline__ void run(SMs& m, const float* dots_s,
                                             const float* unifs_s, float vj) {
    constexpr int P = __builtin_popcount((unsigned)I);
    SN<P>(m) = 1; SS<P>(m) = 1; SP<P>(m) = m.g; m.g++;
    constexpr int M = __builtin_ctz(~(unsigned)I);
    SMerge<P, 0, M>::run(m, dots_s, unifs_s, vj);
    if constexpr (I + 1 < (1 << J))
      SLeaf<J, I + 1>::run(m, dots_s, unifs_s, vj);
  }
};

template <int J>
__device__ __forceinline__ void sm_close(SMs& m, const float* dots_s,
                                         const float* unifs_s, int vj) {
  int n_p = SN<0>(m), s_p = SS<0>(m), th_p = SP<0>(m);
  float q1 = dots_s[m.slot], q2 = dots_s[m.slot + 1];  // (a-o)·r_a, (a-o)·r_o
  m.slot += 2;
  float dm1, dm2;                                      // d = (th_f - th_r)
  if (vj > 0) { dm1 = q2;  dm2 = q1; }
  else        { dm1 = -q1; dm2 = -q2; }
  float au = unifs_s[NNODE + J];
  float ratio = fminf((float)n_p / (float)m.n, 1.0f);
  bool acc = (au < ratio) && (m.s >= 1) && (s_p >= 1);
  if (acc) m.sel = th_p;
  m.n = m.n + ((m.s >= 1) ? n_p : 0);
  m.s = (m.s != 0 && s_p != 0 && (dm1 >= 0.0f) && (dm2 >= 0.0f)) ? 1 : 0;
}

// shared: reduce one chain's partials into dots_s (all TPB threads)
__device__ __forceinline__ void reduce_chain(const float* __restrict__ partials,
                                             int chain, int tid, float* dots_s) {
  const int lane = tid & 63;
  for (int s = (tid >> 6); s < NSLOT; s += TPB / 64) {
    const float4 v4 = *reinterpret_cast<const float4*>(
        partials + ((size_t)s * NCHAIN + chain) * NP + lane * 4);
    float v = (v4.x + v4.y) + (v4.z + v4.w);
    v = wave_sum63(v);
    if (lane == 63) dots_s[s] = v;
  }
}

__device__ __forceinline__ void fill_unifs(int chain, int tid, float* unifs_s,
                                           const Params& P) {
  if (tid < NNODE) unifs_s[tid] = unif_chain(P.nk0[tid], P.nk1[tid], chain);
  else if (tid < NNODE + 5)
    unifs_s[tid] = unif_chain(P.ak0[tid - NNODE], P.ak1[tid - NNODE], chain);
}

__device__ __forceinline__ int run_sm(const float* dots_s, const float* unifs_s,
                                      const Params& P) {
  SMs m;
  m.n = 1; m.s = 1; m.sel = -1; m.slot = 0; m.nodeidx = 0; m.g = 0;
#define SLEVEL(J)                                                              \
  {                                                                            \
    const float vj = (P.v[J] > 0) ? 1.0f : -1.0f;                              \
    SLeaf<J, 0>::run(m, dots_s, unifs_s, vj);                                  \
    sm_close<J>(m, dots_s, unifs_s, P.v[J]);                                   \
  }
  SLEVEL(0) SLEVEL(1) SLEVEL(2) SLEVEL(3) SLEVEL(4)
#undef SLEVEL
  return m.sel;
}

// ---------------- K1: trajectory + dots; tail block: reduce + SM -> sel -----
__launch_bounds__(TPB, 4)
__global__ void k_traj0(const float* __restrict__ th0g, const float* __restrict__ precg,
                        uint32_t kr0, uint32_t kr1,
                        float* __restrict__ partials, float* __restrict__ r0save,
                        unsigned* __restrict__ done, int* __restrict__ selg,
                        unsigned* __restrict__ flagg, Params P) {
  __shared__ float dots_s[NSLOT];
  __shared__ float unifs_s[NNODE + 5];
  __shared__ int sh_last;

  const int tid     = threadIdx.x;
  const int chain   = blockIdx.x / WGPC;
  const int sblk    = blockIdx.x % WGPC;
  const int dimBase = sblk * (TPB * 4) + tid * 4;
  const int lane    = tid & 63;
  const int wv4     = (sblk * 4 + (tid >> 6)) * 4;     // [0,256) step 4
  const uint32_t flat = (uint32_t)chain * NDIM + dimBase;

  Traj t;
  t.th = *reinterpret_cast<const float4*>(th0g + (size_t)chain * NDIM + dimBase);
  t.pc = *reinterpret_cast<const float4*>(precg + dimBase);
  t.r.x = r0_elem(kr0, kr1, flat + 0u);
  t.r.y = r0_elem(kr0, kr1, flat + 1u);
  t.r.z = r0_elem(kr0, kr1, flat + 2u);
  t.r.w = r0_elem(kr0, kr1, flat + 3u);
  *reinterpret_cast<float4*>(r0save + (size_t)flat) = t.r;   // for k_gather
  t.tho = t.th; t.ro = t.r;

  int slot = 0;
  bool cur_fwd = true;

#define LEVEL(J)                                                               \
  {                                                                            \
    const bool fwd = P.v[J] > 0;                                               \
    if (fwd != cur_fwd) {                                                      \
      float4 tmp;                                                              \
      tmp = t.th; t.th = t.tho; t.tho = tmp;                                   \
      tmp = t.r;  t.r  = t.ro;  t.ro  = tmp;                                   \
    }                                                                          \
    cur_fwd = fwd;                                                             \
    const float e  = fwd ? EPS : -EPS;                                         \
    const float he = 0.5f * e;                                                 \
    Leaf<J, 0>::run(t, e, he, partials, chain, wv4, lane, slot);               \
    const float4 df = f4_sub(t.th, t.tho);                                     \
    float p1 = f4_dot(df, t.r);                                                \
    float p2 = f4_dot(df, t.ro);                                               \
    p1 = wave_sum15(p1);                                                       \
    p2 = wave_sum15(p2);                                                       \
    store_partial(partials, slot,     chain, wv4, lane, p1);                   \
    store_partial(partials, slot + 1, chain, wv4, lane, p2);                   \
    slot += 2;                                                                 \
  }

  LEVEL(0) LEVEL(1) LEVEL(2) LEVEL(3) LEVEL(4)
#undef LEVEL

  // ---- arrival: the 16th block of this chain finishes it -------------------
  __threadfence();                       // release this block's partials
  __syncthreads();
  if (tid == 0) {
    unsigned old = __hip_atomic_fetch_add(&done[chain], 1u,
                                          __ATOMIC_ACQ_REL, __HIP_MEMORY_SCOPE_AGENT);
    // ws starts 0xAA-poisoned (harness) or zeroed (fresh pages); any other
    // residue => no winner and k_gather falls back (still correct).
    sh_last = (old == 0xAAAAAAAAu + 15u) || (old == 15u);
  }
  __syncthreads();
  if (!sh_last) return;
  __threadfence();                       // acquire: see other blocks' partials

  reduce_chain(partials, chain, tid, dots_s);
  fill_unifs(chain, tid, unifs_s, P);
  __syncthreads();
  if (tid == 0) {
    selg[chain]  = run_sm(dots_s, unifs_s, P);
    flagg[chain] = MAGIC;
  }
}

// --------- K2: gather — use sel if valid, else local reduce+SM; resim -------
__launch_bounds__(TPB, 4)
__global__ void k_gather(const float* __restrict__ th0g, const float* __restrict__ precg,
                         const float* __restrict__ partials, const float* __restrict__ r0save,
                         const int* __restrict__ selg, const unsigned* __restrict__ flagg,
                         float* __restrict__ outg, Params P) {
  __shared__ float dots_s[NSLOT];
  __shared__ float unifs_s[NNODE + 5];

  const int tid     = threadIdx.x;
  const int chain   = blockIdx.x / WGPC;
  const int sblk    = blockIdx.x % WGPC;
  const int dimBase = sblk * (TPB * 4) + tid * 4;
  const size_t off  = (size_t)chain * NDIM + dimBase;

  int sel;
  if (flagg[chain] == MAGIC) {
    sel = selg[chain];                                 // fast path
  } else {
    // fallback: compute locally (handshake had no winner — unpoisoned ws)
    reduce_chain(partials, chain, tid, dots_s);
    fill_unifs(chain, tid, unifs_s, P);
    __syncthreads();
    sel = run_sm(dots_s, unifs_s, P);
  }

  // ---- re-simulate to the selected leaf, write ----------------------------
  float4 th = *reinterpret_cast<const float4*>(th0g + off);
  float4 outv = th;                                    // default: theta0
  if (sel >= 0) {
    float4 pc = *reinterpret_cast<const float4*>(precg + dimBase);
    float4 r  = *reinterpret_cast<const float4*>(r0save + off);
    float4 tho = th, ro = r;
    int g = 0;
    bool cur_fwd = true;
    bool fin = false;
    for (int j = 0; j < 5 && !fin; ++j) {
      const bool fwd = P.v[j] > 0;
      if (fwd != cur_fwd) {
        float4 tmp;
        tmp = th; th = tho; tho = tmp;
        tmp = r;  r  = ro;  ro  = tmp;
      }
      cur_fwd = fwd;
      const float e  = fwd ? EPS : -EPS;
      const float he = 0.5f * e;
      const int NL = 1 << j;
      for (int i = 0; i < NL; ++i) {
        r  = f4_pcfma(-he, pc, th, r);
        th = f4_fma(e, r, th);
        r  = f4_pcfma(-he, pc, th, r);
        if (g == sel) { outv = th; fin = true; break; }
        g++;
      }
    }
  }
  *reinterpret_cast<float4*>(outg + off) = outv;
}

// ------------------------------------------------------------- host PRNG ---
static inline float host_bits_to_f(uint32_t fb) { float f; std::memcpy(&f, &fb, 4); return f; }

static void host_split(uint32_t k0, uint32_t k1, int nsub, uint32_t* o0, uint32_t* o1) {
#if PARTITIONABLE
  for (int i = 0; i < nsub; ++i) tf2(k0, k1, 0u, (uint32_t)i, o0[i], o1[i]);
#else
  uint32_t A[8], C[8], flat[16];
  for (int i = 0; i < nsub; ++i) tf2(k0, k1, (uint32_t)i, (uint32_t)(nsub + i), A[i], C[i]);
  for (int i = 0; i < nsub; ++i) { flat[i] = A[i]; flat[nsub + i] = C[i]; }
  for (int j = 0; j < nsub; ++j) { o0[j] = flat[2*j]; o1[j] = flat[2*j + 1]; }
#endif
}

static int host_vsign(uint32_t k0, uint32_t k1) {    // sign of normal(kv, ())
  uint32_t a, c; tf2(k0, k1, 0u, 0u, a, c);
#if PARTITIONABLE
  uint32_t bits = a ^ c;
#else
  uint32_t bits = a;
#endif
  float f  = host_bits_to_f((bits >> 9) | 0x3f800000u) - 1.0f;
  float lo = host_bits_to_f(0xBF7FFFFFu);
  float u  = f * 2.0f + lo;                          // sign(erfinv(u)) = sign(u)
  return (u >= 0.0f) ? 1 : -1;
}

// buildtree k3 keys in post-order (merge-consumption order)
static void gen_nodes(uint32_t k0, uint32_t k1, int j,
                      uint32_t* nk0, uint32_t* nk1, int& idx) {
  if (j == 0) return;
  uint32_t o0[3], o1[3];
  host_split(k0, k1, 3, o0, o1);                     // k1, k2, k3
  gen_nodes(o0[0], o1[0], j - 1, nk0, nk1, idx);
  gen_nodes(o0[1], o1[1], j - 1, nk0, nk1, idx);
  nk0[idx] = o0[2]; nk1[idx] = o1[2]; idx++;
}

// ---------------------------------------------------------------- launch ----
extern "C" void kernel_launch(void* const* d_in, const int* in_sizes, int n_in,
                              void* d_out, int out_size, void* d_ws, size_t ws_size,
                              hipStream_t stream) {
  const float* th0  = (const float*)d_in[0];
  const float* prec = (const float*)d_in[1];
  float* out = (float*)d_out;

  float*    partials = (float*)d_ws;                               // 8.1 MB
  float*    r0save   = partials + (size_t)NSLOT * NCHAIN * NP;     // 8 MB
  unsigned* done     = (unsigned*)(r0save + (size_t)NCHAIN * NDIM);
  int*      selg     = (int*)(done + NCHAIN);
  unsigned* flagg    = (unsigned*)(selg + NCHAIN);

  // ---- replicate jax key schedule on host (deterministic, same every call)
  uint32_t key0 = 0u, key1 = 42u;                               // jax.random.key(42)
  uint32_t s0[4], s1[4];
  host_split(key0, key1, 3, s0, s1);                            // kr, ku, key
  const uint32_t kr0 = s0[0], kr1 = s1[0];                      // r0 normals
  key0 = s0[2]; key1 = s1[2];                                   // (ku unused: u==0)

  Params P;
  int idx = 0;
  for (int j = 0; j < 5; ++j) {
    host_split(key0, key1, 4, s0, s1);                          // key, kv, kt, ka
    key0 = s0[0]; key1 = s1[0];
    P.v[j] = host_vsign(s0[1], s1[1]);
    gen_nodes(s0[2], s1[2], j, P.nk0, P.nk1, idx);              // kt recursion
    P.ak0[j] = s0[3]; P.ak1[j] = s1[3];                         // ka
  }

  k_traj0<<<dim3(NCHAIN * WGPC), dim3(TPB), 0, stream>>>(
      th0, prec, kr0, kr1, partials, r0save, done, selg, flagg, P);
  k_gather<<<dim3(NCHAIN * WGPC), dim3(TPB), 0, stream>>>(
      th0, prec, partials, r0save, selg, flagg, out, P);
}

// Round 9
// 103.404 us; speedup vs baseline: 3.8386x; 3.8386x over previous
//
#include <hip/hip_runtime.h>
#include <cstdint>
#include <cstring>

// ============================================================================
// NUTS on diagonal Gaussian, exact JAX-semantics replication.
//
// R8 -> R9: REVERT to the R7 structure (best: 108.6us). R8's tail-block
// handshake put agent-scope fences/atomics in a wide kernel and re-spilled
// the trajectory state (VGPR 36, 270us) — twice-proven failure mode (R5, R8).
// One clean change on top of R7:
//  * The whole JAX key schedule is computed CONSTEXPR at compile time
//    (threefry is pure integer math; the v-sign test folds to bit 31 of the
//    threefry output — exact, no float rounding issue). v[j] become
//    compile-time constants: endpoint-swap branches fold away, e/he are
//    literals, kr keys are immediates, gather resim unrolls per level.
//  * Both kernels keep __launch_bounds__(256,4); 2 dispatches.
// ============================================================================

#define PARTITIONABLE 1

constexpr int NCHAIN = 128;
constexpr int NDIM   = 16384;
constexpr int TPB    = 256;
constexpr int WGPC   = NDIM / (TPB * 4);     // 16 blocks per chain
constexpr int NP     = 256;                  // partial slots per chain-slot
constexpr int NSLOT  = 62;                   // 2*(26 nodes) + 2*(5 doublings)
constexpr int NNODE  = 26;
constexpr float EPS  = 0.05f;

// ------------------------------------------------- threefry (constexpr-able)
__host__ __device__ constexpr void tf2(uint32_t k0, uint32_t k1,
                                       uint32_t x0, uint32_t x1,
                                       uint32_t& o0, uint32_t& o1) {
  const uint32_t ks2 = k0 ^ k1 ^ 0x1BD11BDAu;
  x0 += k0; x1 += k1;
#define TF_R(r) { x0 += x1; x1 = (x1 << (r)) | (x1 >> (32 - (r))); x1 ^= x0; }
  TF_R(13) TF_R(15) TF_R(26) TF_R(6)
  x0 += k1;  x1 += ks2 + 1u;
  TF_R(17) TF_R(29) TF_R(16) TF_R(24)
  x0 += ks2; x1 += k0 + 2u;
  TF_R(13) TF_R(15) TF_R(26) TF_R(6)
  x0 += k0;  x1 += k1 + 3u;
  TF_R(17) TF_R(29) TF_R(16) TF_R(24)
  x0 += k1;  x1 += ks2 + 4u;
  TF_R(13) TF_R(15) TF_R(26) TF_R(6)
  x0 += ks2; x1 += k0 + 5u;
#undef TF_R
  o0 = x0; o1 = x1;
}

// ------------------------------------ compile-time JAX key schedule ---------
struct Sched {
  uint32_t kr0, kr1;                // r0 normal key
  int      v[5];                    // doubling direction signs
  uint32_t nk0[NNODE], nk1[NNODE];  // buildtree k3 keys, post-order across j
  uint32_t ak0[5], ak1[5];          // main-loop ka keys
};

__host__ __device__ constexpr void csplit(uint32_t k0, uint32_t k1, int nsub,
                                          uint32_t* o0, uint32_t* o1) {
#if PARTITIONABLE
  for (int i = 0; i < nsub; ++i) tf2(k0, k1, 0u, (uint32_t)i, o0[i], o1[i]);
#else
  uint32_t A[8] = {}, C[8] = {}, flat[16] = {};
  for (int i = 0; i < nsub; ++i) tf2(k0, k1, (uint32_t)i, (uint32_t)(nsub + i), A[i], C[i]);
  for (int i = 0; i < nsub; ++i) { flat[i] = A[i]; flat[nsub + i] = C[i]; }
  for (int j = 0; j < nsub; ++j) { o0[j] = flat[2*j]; o1[j] = flat[2*j + 1]; }
#endif
}

__host__ __device__ constexpr void cgen_nodes(uint32_t k0, uint32_t k1, int j,
                                              uint32_t* nk0, uint32_t* nk1, int& idx) {
  if (j == 0) return;
  uint32_t o0[3] = {}, o1[3] = {};
  csplit(k0, k1, 3, o0, o1);                         // k1, k2, k3
  cgen_nodes(o0[0], o1[0], j - 1, nk0, nk1, idx);
  cgen_nodes(o0[1], o1[1], j - 1, nk0, nk1, idx);
  nk0[idx] = o0[2]; nk1[idx] = o1[2]; idx++;
}

__host__ __device__ constexpr Sched make_sched() {
  Sched S{};
  uint32_t key0 = 0u, key1 = 42u;                    // jax.random.key(42)
  uint32_t s0[4] = {}, s1[4] = {};
  csplit(key0, key1, 3, s0, s1);                     // kr, ku, key
  S.kr0 = s0[0]; S.kr1 = s1[0];
  key0 = s0[2]; key1 = s1[2];                        // (ku unused: u==0)
  int idx = 0;
  for (int j = 0; j < 5; ++j) {
    csplit(key0, key1, 4, s0, s1);                   // key, kv, kt, ka
    key0 = s0[0]; key1 = s1[0];
    uint32_t a = 0, c = 0;
    tf2(s0[1], s1[1], 0u, 0u, a, c);                 // normal(kv, ()) bits
#if PARTITIONABLE
    uint32_t bits = a ^ c;
#else
    uint32_t bits = a;
#endif
    // sign(sqrt2*erfinv(u01(bits)*2+lo)) == sign(u) == bit 31 of bits (exact:
    // u = (4k - (2^24-1))/2^24 with k=bits>>9; numerator odd => sign test is
    // k >= 2^22 <=> bits >= 2^31; float rounding cannot flip an odd numerator)
    S.v[j] = (bits >> 31) ? 1 : -1;
    cgen_nodes(s0[2], s1[2], j, S.nk0, S.nk1, idx);  // kt recursion
    S.ak0[j] = s0[3]; S.ak1[j] = s1[3];              // ka
  }
  return S;
}

constexpr Sched SCHED = make_sched();

// ---------------------------------------------------------- device PRNG ----
__device__ static inline float u01(uint32_t bits) {
  return __uint_as_float((bits >> 9) | 0x3f800000u) - 1.0f;
}

// XLA ErfInv32 (Giles), fma-exact
__device__ static inline float erfinv32(float x) {
  float w = -log1pf(-x * x);
  float p;
  if (w < 5.0f) {
    w -= 2.5f;
    p = 2.81022636e-08f;
    p = fmaf(p, w, 3.43273939e-07f);
    p = fmaf(p, w, -3.5233877e-06f);
    p = fmaf(p, w, -4.39150654e-06f);
    p = fmaf(p, w, 0.00021858087f);
    p = fmaf(p, w, -0.00125372503f);
    p = fmaf(p, w, -0.00417768164f);
    p = fmaf(p, w, 0.246640727f);
    p = fmaf(p, w, 1.50140941f);
  } else {
    w = sqrtf(w) - 3.0f;
    p = -0.000200214257f;
    p = fmaf(p, w, 0.000100950558f);
    p = fmaf(p, w, 0.00134934322f);
    p = fmaf(p, w, -0.00367342844f);
    p = fmaf(p, w, 0.00573950773f);
    p = fmaf(p, w, -0.0076224613f);
    p = fmaf(p, w, 0.00943887047f);
    p = fmaf(p, w, 1.00167406f);
    p = fmaf(p, w, 2.83297682f);
  }
  return p * x;
}

__device__ static inline float norm_from_bits(uint32_t bits) {
  const float lo = __uint_as_float(0xBF7FFFFFu);       // -(1 - 2^-24)
  float u = fmaxf(lo, fmaf(u01(bits), 2.0f, lo));
  return __uint_as_float(0x3FB504F3u) * erfinv32(u);   // sqrt(2) in f32
}

__device__ static inline float r0_elem(uint32_t i) {   // keys are immediates
#if PARTITIONABLE
  uint32_t a, c; tf2(SCHED.kr0, SCHED.kr1, 0u, i, a, c);
  return norm_from_bits(a ^ c);
#else
  const uint32_t H = (uint32_t)(NCHAIN * NDIM / 2);
  uint32_t a, c;
  if (i < H) { tf2(SCHED.kr0, SCHED.kr1, i, i + H, a, c); return norm_from_bits(a); }
  else       { tf2(SCHED.kr0, SCHED.kr1, i - H, i, a, c); return norm_from_bits(c); }
#endif
}

__device__ static inline float unif_chain(uint32_t k0, uint32_t k1, int b) {
#if PARTITIONABLE
  uint32_t a, c; tf2(k0, k1, 0u, (uint32_t)b, a, c);
  return u01(a ^ c);
#else
  uint32_t a, c;
  if (b < 64) { tf2(k0, k1, (uint32_t)b, (uint32_t)(b + 64), a, c); return u01(a); }
  else        { tf2(k0, k1, (uint32_t)(b - 64), (uint32_t)b, a, c); return u01(c); }
#endif
}

// ------------------------------------------------------------- DPP sums -----
#define DPP_ADD(x, ctrl, rm)                                                   \
  (x) += __int_as_float(__builtin_amdgcn_update_dpp(                           \
      0, __float_as_int(x), (ctrl), (rm), 0xf, true));

__device__ static inline float wave_sum63(float x) {   // full 64-lane, lane 63
  DPP_ADD(x, 0x111, 0xf)
  DPP_ADD(x, 0x112, 0xf)
  DPP_ADD(x, 0x114, 0xf)
  DPP_ADD(x, 0x118, 0xf)
  DPP_ADD(x, 0x142, 0xa)   // row_bcast:15 -> rows 1,3
  DPP_ADD(x, 0x143, 0xc)   // row_bcast:31 -> rows 2,3
  return x;
}
__device__ static inline float wave_sum15(float x) {   // row-of-16 sums, lane 15
  DPP_ADD(x, 0x111, 0xf)
  DPP_ADD(x, 0x112, 0xf)
  DPP_ADD(x, 0x114, 0xf)
  DPP_ADD(x, 0x118, 0xf)
  return x;
}

// ------------------------------------------------------- float4 arithmetic --
__device__ __forceinline__ float4 f4_pcfma(float he, const float4& pc,
                                           const float4& th, const float4& r) {
  return make_float4(fmaf(he, pc.x * th.x, r.x), fmaf(he, pc.y * th.y, r.y),
                     fmaf(he, pc.z * th.z, r.z), fmaf(he, pc.w * th.w, r.w));
}
__device__ __forceinline__ float4 f4_fma(float e, const float4& a, const float4& b) {
  return make_float4(fmaf(e, a.x, b.x), fmaf(e, a.y, b.y),
                     fmaf(e, a.z, b.z), fmaf(e, a.w, b.w));
}
__device__ __forceinline__ float4 f4_sub(const float4& a, const float4& b) {
  return make_float4(a.x - b.x, a.y - b.y, a.z - b.z, a.w - b.w);
}
__device__ __forceinline__ float f4_dot(const float4& a, const float4& b) {
  float d = a.x * b.x;
  d = fmaf(a.y, b.y, d);
  d = fmaf(a.z, b.z, d);
  d = fmaf(a.w, b.w, d);
  return d;
}

// ------------------------------- trajectory state: NAMED float4 vars only ---
struct Traj {
  float4 th, r, tho, ro, pc;
  float4 nt0, nt1, nt2, nt3, nt4;
  float4 nr0, nr1, nr2, nr3, nr4;
};
template <int L> __device__ __forceinline__ float4& NT(Traj& t) {
  if constexpr (L == 0) return t.nt0; else if constexpr (L == 1) return t.nt1;
  else if constexpr (L == 2) return t.nt2; else if constexpr (L == 3) return t.nt3;
  else return t.nt4;
}
template <int L> __device__ __forceinline__ float4& NR(Traj& t) {
  if constexpr (L == 0) return t.nr0; else if constexpr (L == 1) return t.nr1;
  else if constexpr (L == 2) return t.nr2; else if constexpr (L == 3) return t.nr3;
  else return t.nr4;
}

// store one slot's row partials (4 per wave): pos = wv4 + row
__device__ __forceinline__ void store_partial(float* __restrict__ partials,
                                              int slot, int chain, int wv4,
                                              int lane, float v) {
  if ((lane & 15) == 15)
    partials[((size_t)slot * NCHAIN + chain) * NP + wv4 + (lane >> 4)] = v;
}

// merges after a leaf: K = 0..M-1, all indices constexpr
template <int P, int K, int M>
struct Merge {
  static __device__ __forceinline__ void run(Traj& t, float* __restrict__ partials,
                                             int chain, int wv4, int lane, int& slot) {
    if constexpr (K < M) {
      const float4 df = f4_sub(t.th, NT<P - 1 - K>(t));
      float d1 = f4_dot(df, NR<P - 1 - K>(t));   // (th_far-th_near)·r_near
      float d2 = f4_dot(df, t.r);                // (th_far-th_near)·r_far
      d1 = wave_sum15(d1);
      d2 = wave_sum15(d2);
      store_partial(partials, slot,     chain, wv4, lane, d1);
      store_partial(partials, slot + 1, chain, wv4, lane, d2);
      slot += 2;
      Merge<P, K + 1, M>::run(t, partials, chain, wv4, lane, slot);
    }
  }
};

template <int J, int I>
struct Leaf {
  static __device__ __forceinline__ void run(Traj& t, float e, float he,
                                             float* __restrict__ partials,
                                             int chain, int wv4, int lane, int& slot) {
    t.r  = f4_pcfma(-he, t.pc, t.th, t.r);
    t.th = f4_fma(e, t.r, t.th);
    t.r  = f4_pcfma(-he, t.pc, t.th, t.r);
    constexpr int P = __builtin_popcount((unsigned)I);
    NT<P>(t) = t.th; NR<P>(t) = t.r;
    constexpr int M = __builtin_ctz(~(unsigned)I);
    Merge<P, 0, M>::run(t, partials, chain, wv4, lane, slot);
    if constexpr (I + 1 < (1 << J))
      Leaf<J, I + 1>::run(t, e, he, partials, chain, wv4, lane, slot);
  }
};

// ----------------------------------------------- K1: trajectory, dots mode --
__launch_bounds__(TPB, 4)
__global__ void k_traj0(const float* __restrict__ th0g, const float* __restrict__ precg,
                        float* __restrict__ partials, float* __restrict__ r0save) {
  const int tid     = threadIdx.x;
  const int chain   = blockIdx.x / WGPC;
  const int sblk    = blockIdx.x % WGPC;
  const int dimBase = sblk * (TPB * 4) + tid * 4;
  const int lane    = tid & 63;
  const int wv4     = (sblk * 4 + (tid >> 6)) * 4;     // [0,256) step 4
  const uint32_t flat = (uint32_t)chain * NDIM + dimBase;

  Traj t;
  t.th = *reinterpret_cast<const float4*>(th0g + (size_t)chain * NDIM + dimBase);
  t.pc = *reinterpret_cast<const float4*>(precg + dimBase);
  t.r.x = r0_elem(flat + 0u);
  t.r.y = r0_elem(flat + 1u);
  t.r.z = r0_elem(flat + 2u);
  t.r.w = r0_elem(flat + 3u);
  *reinterpret_cast<float4*>(r0save + (size_t)flat) = t.r;   // for k_gather
  t.tho = t.th; t.ro = t.r;

  int slot = 0;

#define LEVEL(J)                                                               \
  {                                                                            \
    constexpr bool fwd = SCHED.v[J] > 0;                                       \
    constexpr bool prv = (J == 0) ? true : (SCHED.v[(J == 0) ? 0 : J - 1] > 0);\
    if constexpr (fwd != prv) {                                                \
      float4 tmp;                                                              \
      tmp = t.th; t.th = t.tho; t.tho = tmp;                                   \
      tmp = t.r;  t.r  = t.ro;  t.ro  = tmp;                                   \
    }                                                                          \
    constexpr float e  = fwd ? EPS : -EPS;                                     \
    constexpr float he = 0.5f * e;                                             \
    Leaf<J, 0>::run(t, e, he, partials, chain, wv4, lane, slot);               \
    const float4 df = f4_sub(t.th, t.tho);                                     \
    float p1 = f4_dot(df, t.r);                                                \
    float p2 = f4_dot(df, t.ro);                                               \
    p1 = wave_sum15(p1);                                                       \
    p2 = wave_sum15(p2);                                                       \
    store_partial(partials, slot,     chain, wv4, lane, p1);                   \
    store_partial(partials, slot + 1, chain, wv4, lane, p2);                   \
    slot += 2;                                                                 \
  }

  LEVEL(0) LEVEL(1) LEVEL(2) LEVEL(3) LEVEL(4)
#undef LEVEL
}

// ------------------------- state machine: NAMED scalar slots + templates ----
struct SMs {
  int n0, s0, p0, n1, s1, p1, n2, s2, p2, n3, s3, p3, n4, s4, p4;
  int n, s, sel, slot, nodeidx, g;
};
template <int L> __device__ __forceinline__ int& SN(SMs& m) {
  if constexpr (L == 0) return m.n0; else if constexpr (L == 1) return m.n1;
  else if constexpr (L == 2) return m.n2; else if constexpr (L == 3) return m.n3;
  else return m.n4;
}
template <int L> __device__ __forceinline__ int& SS(SMs& m) {
  if constexpr (L == 0) return m.s0; else if constexpr (L == 1) return m.s1;
  else if constexpr (L == 2) return m.s2; else if constexpr (L == 3) return m.s3;
  else return m.s4;
}
template <int L> __device__ __forceinline__ int& SP(SMs& m) {
  if constexpr (L == 0) return m.p0; else if constexpr (L == 1) return m.p1;
  else if constexpr (L == 2) return m.p2; else if constexpr (L == 3) return m.p3;
  else return m.p4;
}

template <int P, int K, int M>
struct SMerge {
  static __device__ __forceinline__ void run(SMs& m, const float* dots_s,
                                             const float* unifs_s, float vj) {
    if constexpr (K < M) {
      constexpr int T = P - K;                       // second subtree slot
      int n1 = SN<T-1>(m), s1 = SS<T-1>(m), p1 = SP<T-1>(m);
      int n2 = SN<T>(m),   s2 = SS<T>(m),   p2 = SP<T>(m);
      float d1 = dots_s[m.slot], d2 = dots_s[m.slot + 1];
      m.slot += 2;
      float uu = unifs_s[m.nodeidx]; m.nodeidx++;
      int dn = n1 + n2; if (dn < 1) dn = 1;
      bool fl = (uu < (float)n2 / (float)dn) && (s1 >= 1);
      SP<T-1>(m) = fl ? p2 : p1;
      SS<T-1>(m) = (s1 != 0 && s2 != 0 &&
                    (vj * d1 >= 0.0f) && (vj * d2 >= 0.0f)) ? 1 : 0;
      SN<T-1>(m) = n1 + ((s1 >= 1) ? n2 : 0);
      SMerge<P, K + 1, M>::run(m, dots_s, unifs_s, vj);
    }
  }
};

template <int J, int I>
struct SLeaf {
  static __device__ __forceinline__ void run(SMs& m, const float* dots_s,
                                             const float* unifs_s, float vj) {
    constexpr int P = __builtin_popcount((unsigned)I);
    SN<P>(m) = 1; SS<P>(m) = 1; SP<P>(m) = m.g; m.g++;
    constexpr int M = __builtin_ctz(~(unsigned)I);
    SMerge<P, 0, M>::run(m, dots_s, unifs_s, vj);
    if constexpr (I + 1 < (1 << J))
      SLeaf<J, I + 1>::run(m, dots_s, unifs_s, vj);
  }
};

template <int J>
__device__ __forceinline__ void sm_close(SMs& m, const float* dots_s,
                                         const float* unifs_s) {
  constexpr int vj = SCHED.v[J];
  int n_p = SN<0>(m), s_p = SS<0>(m), th_p = SP<0>(m);
  float q1 = dots_s[m.slot], q2 = dots_s[m.slot + 1];  // (a-o)·r_a, (a-o)·r_o
  m.slot += 2;
  float dm1, dm2;                                      // d = (th_f - th_r)
  if constexpr (vj > 0) { dm1 = q2;  dm2 = q1; }
  else                  { dm1 = -q1; dm2 = -q2; }
  float au = unifs_s[NNODE + J];
  float ratio = fminf((float)n_p / (float)m.n, 1.0f);
  bool acc = (au < ratio) && (m.s >= 1) && (s_p >= 1);
  if (acc) m.sel = th_p;
  m.n = m.n + ((m.s >= 1) ? n_p : 0);
  m.s = (m.s != 0 && s_p != 0 && (dm1 >= 0.0f) && (dm2 >= 0.0f)) ? 1 : 0;
}

// shared: reduce one chain's partials into dots_s (all TPB threads)
__device__ __forceinline__ void reduce_chain(const float* __restrict__ partials,
                                             int chain, int tid, float* dots_s) {
  const int lane = tid & 63;
  for (int s = (tid >> 6); s < NSLOT; s += TPB / 64) {
    const float4 v4 = *reinterpret_cast<const float4*>(
        partials + ((size_t)s * NCHAIN + chain) * NP + lane * 4);
    float v = (v4.x + v4.y) + (v4.z + v4.w);
    v = wave_sum63(v);
    if (lane == 63) dots_s[s] = v;
  }
}

__device__ __forceinline__ void fill_unifs(int chain, int tid, float* unifs_s) {
  if (tid < NNODE) unifs_s[tid] = unif_chain(SCHED.nk0[tid], SCHED.nk1[tid], chain);
  else if (tid < NNODE + 5)
    unifs_s[tid] = unif_chain(SCHED.ak0[tid - NNODE], SCHED.ak1[tid - NNODE], chain);
}

__device__ __forceinline__ int run_sm(const float* dots_s, const float* unifs_s) {
  SMs m;
  m.n = 1; m.s = 1; m.sel = -1; m.slot = 0; m.nodeidx = 0; m.g = 0;
#define SLEVEL(J)                                                              \
  {                                                                            \
    constexpr float vj = (SCHED.v[J] > 0) ? 1.0f : -1.0f;                      \
    SLeaf<J, 0>::run(m, dots_s, unifs_s, vj);                                  \
    sm_close<J>(m, dots_s, unifs_s);                                           \
  }
  SLEVEL(0) SLEVEL(1) SLEVEL(2) SLEVEL(3) SLEVEL(4)
#undef SLEVEL
  return m.sel;
}

// --------- K2: per-block reduce + state machine + gather (2048 blocks) ------
__launch_bounds__(TPB, 4)
__global__ void k_gather(const float* __restrict__ th0g, const float* __restrict__ precg,
                         const float* __restrict__ partials, const float* __restrict__ r0save,
                         float* __restrict__ outg) {
  __shared__ float dots_s[NSLOT];
  __shared__ float unifs_s[NNODE + 5];

  const int tid     = threadIdx.x;
  const int chain   = blockIdx.x / WGPC;
  const int sblk    = blockIdx.x % WGPC;
  const int dimBase = sblk * (TPB * 4) + tid * 4;
  const size_t off  = (size_t)chain * NDIM + dimBase;

  // ---- reduce this chain's partials into LDS (redundant per block) ---------
  reduce_chain(partials, chain, tid, dots_s);
  fill_unifs(chain, tid, unifs_s);
  __syncthreads();

  // ---- state machine (all threads, LDS broadcast reads) --------------------
  const int sel = run_sm(dots_s, unifs_s);

  // ---- re-simulate to the selected leaf, write ----------------------------
  float4 th = *reinterpret_cast<const float4*>(th0g + off);
  float4 outv = th;                                    // default: theta0
  if (sel >= 0) {
    float4 pc = *reinterpret_cast<const float4*>(precg + dimBase);
    float4 r  = *reinterpret_cast<const float4*>(r0save + off);
    float4 tho = th, ro = r;
    int g = 0;
    bool fin = false;

#define GLEVEL(J)                                                              \
    if (!fin) {                                                                \
      constexpr bool fwd = SCHED.v[J] > 0;                                     \
      constexpr bool prv = (J == 0) ? true                                     \
                                    : (SCHED.v[(J == 0) ? 0 : J - 1] > 0);     \
      if constexpr (fwd != prv) {                                              \
        float4 tmp;                                                            \
        tmp = th; th = tho; tho = tmp;                                         \
        tmp = r;  r  = ro;  ro  = tmp;                                         \
      }                                                                        \
      constexpr float e  = fwd ? EPS : -EPS;                                   \
      constexpr float he = 0.5f * e;                                           \
      for (int i = 0; i < (1 << J); ++i) {                                     \
        r  = f4_pcfma(-he, pc, th, r);                                         \
        th = f4_fma(e, r, th);                                                 \
        r  = f4_pcfma(-he, pc, th, r);                                         \
        if (g == sel) { outv = th; fin = true; break; }                        \
        g++;                                                                   \
      }                                                                        \
    }

    GLEVEL(0) GLEVEL(1) GLEVEL(2) GLEVEL(3) GLEVEL(4)
#undef GLEVEL
  }
  *reinterpret_cast<float4*>(outg + off) = outv;
}

// ---------------------------------------------------------------- launch ----
extern "C" void kernel_launch(void* const* d_in, const int* in_sizes, int n_in,
                              void* d_out, int out_size, void* d_ws, size_t ws_size,
                              hipStream_t stream) {
  const float* th0  = (const float*)d_in[0];
  const float* prec = (const float*)d_in[1];
  float* out = (float*)d_out;

  float* partials = (float*)d_ws;                               // 8.1 MB
  float* r0save   = partials + (size_t)NSLOT * NCHAIN * NP;     // 8 MB

  k_traj0<<<dim3(NCHAIN * WGPC), dim3(TPB), 0, stream>>>(
      th0, prec, partials, r0save);
  k_gather<<<dim3(NCHAIN * WGPC), dim3(TPB), 0, stream>>>(
      th0, prec, partials, r0save, out);
}